// Round 9
// baseline (163.177 us; speedup 1.0000x reference)
//
#include <hip/hip_runtime.h>
#include <math.h>

#define B_  8
#define N_  128
#define T_  256
#define L_  32
#define H_  128
#define TT_ 224   // T - L

typedef float f4    __attribute__((ext_vector_type(4)));
typedef float f32x4 __attribute__((ext_vector_type(4)));
typedef short bf16x8 __attribute__((ext_vector_type(8)));

__device__ __forceinline__ unsigned pk2bf(float a, float b) {   // RNE bf16 pack
    unsigned ua = __float_as_uint(a), ub = __float_as_uint(b);
    ua = (ua + 0x7FFFu + ((ua >> 16) & 1u)) >> 16;
    ub = (ub + 0x7FFFu + ((ub >> 16) & 1u)) >> 16;
    return ua | (ub << 16);
}

// ---------------------------------------------------------------------------
// Kernel 0, grid (N, 7) x 256 (unchanged from R8 — correct & fast):
//  y=0..5: W_ih -> bf16 W3sw pre-swizzled per-lane MFMA B-frag order.
//  y=6:    wsum / bsum / fused bias.
// ---------------------------------------------------------------------------
__global__ __launch_bounds__(256)
void k_pre(const float* __restrict__ W_ih, const float* __restrict__ W_fc,
           const float* __restrict__ b_ih, const float* __restrict__ b_hh,
           const float* __restrict__ b_fc,
           unsigned short* __restrict__ W3sw, float* __restrict__ wsum,
           float* __restrict__ bsum, float* __restrict__ bia_g) {
    const int n   = blockIdx.x;
    const int pid = blockIdx.y;   // 0..6
    const int tid = threadIdx.x;
    if (pid < 6) {
        const int idx  = pid * 256 + tid;          // 0..1535
        const int fg   = idx >> 6;                 // 0..23
        const int lane = idx & 63;
        const int col  = lane & 15, quad = lane >> 4;
        const int g    = fg % 3, ht = fg / 3;
        const int r    = g * 128 + ht * 16 + col;
        const int sr   = r + (r >= 128 ? 128 : 0);
        const f4* src = (const f4*)(W_ih + (size_t)n * 512 * L_ + sr * L_ + quad * 8);
        f4 v0 = src[0], v1 = src[1];
        uint4 out;
        out.x = pk2bf(v0.x, v0.y); out.y = pk2bf(v0.z, v0.w);
        out.z = pk2bf(v1.x, v1.y); out.w = pk2bf(v1.z, v1.w);
        *(uint4*)&W3sw[((size_t)n * 1536 + idx) * 8] = out;
    } else {
        __shared__ f4 part[8][32];
        __shared__ float bp[2];
        {   // wsum: thread (jg=tid>>5, h4=tid&31) sums 16 j
            const int h4 = tid & 31, jg = tid >> 5;
            const f4* Wf = (const f4*)(W_fc + (size_t)n * N_ * H_) + (size_t)jg * 16 * 32 + h4;
            f4 s = {0.f, 0.f, 0.f, 0.f};
            #pragma unroll
            for (int j = 0; j < 16; ++j) s += Wf[j * 32];
            part[jg][h4] = s;
        }
        if (tid < 128) {   // bsum partials
            float bv = b_fc[n * N_ + tid];
            #pragma unroll
            for (int off = 32; off > 0; off >>= 1) bv += __shfl_down(bv, off, 64);
            if ((tid & 63) == 0) bp[tid >> 6] = bv;
        }
        for (int i = tid; i < 384; i += 256) {
            const int sr = i + (i >= 128 ? 128 : 0);
            bia_g[n * 384 + i] = b_ih[(size_t)n * 512 + sr] + b_hh[(size_t)n * 512 + sr];
        }
        __syncthreads();
        if (tid < 32) {
            f4 s = part[0][tid];
            #pragma unroll
            for (int jg = 1; jg < 8; ++jg) s += part[jg][tid];
            *(f4*)&wsum[n * H_ + tid * 4] = s;
        }
        if (tid == 0) bsum[n] = bp[0] + bp[1];
    }
}

// ---------------------------------------------------------------------------
// Kernel 1: per (n,b) block, 4 waves. Changes vs R8:
//  - X_hat reduction: per-ttile 16x ds_bpermute + 16 add  ->  4x ds_add_f32
//    into xh_acc[224][20] (stride 20: lane pattern is 2-way banked = free;
//    rows 16B-aligned for the final f4 row-sum). The bpermutes were the
//    surviving 725K SQ_LDS_BANK_CONFLICT + ~25% of VALU issue.
//  - Activations: fused-rcp exact form, 2 rcp instead of 4 per element:
//    sig(a)*tanh(b) = (e2-1) * rcp((1+e1)*(e2+1)), e1=e^-a, e2=e^2b.
//    Overflow-safe: |gates| <= ~3 for this input distribution.
//  - #pragma unroll 2 on ttile loop for cross-tile ILP.
// ---------------------------------------------------------------------------
__global__ __launch_bounds__(256)
__attribute__((amdgpu_waves_per_eu(4, 4)))
void k_main(const float* __restrict__ x,
            const unsigned short* __restrict__ W3sw,
            const float* __restrict__ bia_g,
            const float* __restrict__ wsum, const float* __restrict__ bsum,
            const float* __restrict__ W_fc, const float* __restrict__ b_fc,
            float* __restrict__ G, float* __restrict__ xhat) {
    const int n   = blockIdx.x;
    const int b   = blockIdx.y;
    const int tid = threadIdx.x;
    const int w    = tid >> 6;    // wave 0..3
    const int lane = tid & 63;
    const int col  = lane & 15;   // MFMA m/n index
    const int quad = lane >> 4;   // MFMA k-group / row-group

    __shared__ float xs[258];
    __shared__ unsigned xeo[2][128];   // bf16 pairs: [0]=even-start, [1]=shift-1
    __shared__ float xr[TT_];
    __shared__ float xh_acc[TT_ * 20]; // stride 20 floats (80B, 16B-aligned rows)
    __shared__ float hd_loc[H_];
    __shared__ float red[4];

    // ---- B-frags: 6 coalesced 16B loads (pre-swizzled) ----
    const uint4* wsw = (const uint4*)W3sw + (size_t)n * 24 * 64 + lane;
    union { uint4 u; bf16x8 v; } bfr[2][3];
    float biaL[2][3], wshL[2];
    #pragma unroll
    for (int ht2 = 0; ht2 < 2; ++ht2) {
        const int ht = 2 * w + ht2;
        #pragma unroll
        for (int g = 0; g < 3; ++g) {
            bfr[ht2][g].u = wsw[(size_t)(ht * 3 + g) * 64];
            biaL[ht2][g]  = bia_g[n * 384 + g * 128 + ht * 16 + col];
        }
        wshL[ht2] = wsum[n * H_ + ht * 16 + col];
    }
    const float bsum_n = bsum[n];

    // ---- stage x; zero xh_acc ----
    xs[tid] = x[((size_t)b * N_ + n) * T_ + tid];
    if (tid < 2) xs[256 + tid] = 0.f;
    for (int i = tid; i < TT_ * 20; i += 256) xh_acc[i] = 0.f;
    __syncthreads();
    if (tid < TT_) xr[tid] = 1.0f / xs[L_ + tid];
    if (tid < 128) {
        xeo[0][tid] = pk2bf(xs[2 * tid],     xs[2 * tid + 1]);
        xeo[1][tid] = pk2bf(xs[2 * tid + 1], xs[2 * tid + 2]);
    }
    __syncthreads();

    float hd_acc[2] = {0.f, 0.f};
    const f32x4 zero4 = {0.f, 0.f, 0.f, 0.f};

    #pragma unroll 2
    for (int ttile = 0; ttile < 14; ++ttile) {
        // A-frag: x[s..s+7] as bf16, s = ttile*16 + col + quad*8
        const int s = ttile * 16 + col + quad * 8;
        const int p = s & 1, base = s >> 1;
        union { unsigned u[4]; bf16x8 v; } af;
        #pragma unroll
        for (int q = 0; q < 4; ++q) af.u[q] = xeo[p][base + q];

        const f4 xr4 = *(const f4*)&xr[ttile * 16 + quad * 4];
        float px[4] = {0.f, 0.f, 0.f, 0.f};

        #pragma unroll
        for (int ht2 = 0; ht2 < 2; ++ht2) {
            f32x4 ai = __builtin_amdgcn_mfma_f32_16x16x32_bf16(af.v, bfr[ht2][0].v, zero4, 0, 0, 0);
            f32x4 ag = __builtin_amdgcn_mfma_f32_16x16x32_bf16(af.v, bfr[ht2][1].v, zero4, 0, 0, 0);
            f32x4 ao = __builtin_amdgcn_mfma_f32_16x16x32_bf16(af.v, bfr[ht2][2].v, zero4, 0, 0, 0);
            #pragma unroll
            for (int reg = 0; reg < 4; ++reg) {
                const float gi = ai[reg] + biaL[ht2][0];
                const float gg = ag[reg] + biaL[ht2][1];
                const float go = ao[reg] + biaL[ht2][2];
                // c = sig(gi)*tanh(gg), fused single-rcp form (exact)
                const float e1 = __expf(-gi);
                const float e2 = __expf(gg + gg);
                const float c  = (e2 - 1.f) *
                    __builtin_amdgcn_rcpf((1.f + e1) * (e2 + 1.f));
                // hh = sig(go)*tanh(c)
                const float e3 = __expf(-go);
                const float e4 = __expf(c + c);
                const float hh = (e4 - 1.f) *
                    __builtin_amdgcn_rcpf((1.f + e3) * (e4 + 1.f));
                hd_acc[ht2] = fmaf(hh, xr4[reg], hd_acc[ht2]);
                px[reg]     = fmaf(hh, wshL[ht2], px[reg]);
            }
        }
        // X_hat partial accumulate: one ds_add_f32 per reg (64 distinct
        // (t,col) addresses per wave; stride-20 -> 2-way banked = free)
        #pragma unroll
        for (int reg = 0; reg < 4; ++reg)
            atomicAdd(&xh_acc[(ttile * 16 + quad * 4 + reg) * 20 + col], px[reg]);
    }

    // ---- Hd -> LDS (reduce across quads), Dinv partials ----
    #pragma unroll
    for (int ht2 = 0; ht2 < 2; ++ht2) {
        float v = hd_acc[ht2];
        v += __shfl_xor(v, 16, 64);
        v += __shfl_xor(v, 32, 64);
        if (lane < 16) hd_loc[(2 * w + ht2) * 16 + lane] = v;
    }
    {
        float dv = (tid < TT_) ? xr[tid] : 0.f;
        #pragma unroll
        for (int off = 32; off > 0; off >>= 1) dv += __shfl_down(dv, off, 64);
        if (lane == 0) red[w] = dv;
    }
    __syncthreads();

    // ---- X_hat writeout: sum 16 cols of the row ----
    if (tid < TT_) {
        const float* row = &xh_acc[tid * 20];
        const f4 a = *(const f4*)row + *(const f4*)(row + 4) +
                     *(const f4*)(row + 8) + *(const f4*)(row + 12);
        xhat[((size_t)b * TT_ + tid) * N_ + n] =
            (a[0] + a[1] + a[2] + a[3]) + bsum_n + 1e-6f;
    }

    // ---- fused G epilogue: thread pair (j, half) sums 64 h each ----
    {
        const float dinv = red[0] + red[1] + red[2] + red[3];
        const int j    = tid >> 1;
        const int half = tid & 1;
        const f4* Wf = (const f4*)(W_fc + ((size_t)n * N_ + j) * H_ + half * 64);
        float s = 0.f;
        #pragma unroll
        for (int q = 0; q < 16; ++q) {
            const f4 wv = Wf[q];
            const int hb = half * 64 + q * 4;
            s = fmaf(wv.x, hd_loc[hb + 0],
                fmaf(wv.y, hd_loc[hb + 1],
                fmaf(wv.z, hd_loc[hb + 2],
                fmaf(wv.w, hd_loc[hb + 3], s))));
        }
        s += __shfl_xor(s, 1, 64);
        if (half == 0) {
            const float bj = b_fc[n * N_ + j];
            G[(size_t)b * N_ * N_ + (size_t)j * N_ + n] =
                (s + bj * dinv) * (1.0f / 224.0f);
        }
    }
}

// ---------------------------------------------------------------------------
extern "C" void kernel_launch(void* const* d_in, const int* in_sizes, int n_in,
                              void* d_out, int out_size, void* d_ws, size_t ws_size,
                              hipStream_t stream) {
    const float* x    = (const float*)d_in[0];
    const float* W_ih = (const float*)d_in[1];
    const float* b_ih = (const float*)d_in[2];
    const float* b_hh = (const float*)d_in[3];
    const float* W_fc = (const float*)d_in[4];
    const float* b_fc = (const float*)d_in[5];

    float* G    = (float*)d_out;                        // B*N*N = 131072
    float* xhat = (float*)d_out + (size_t)B_ * N_ * N_; // B*TT*N = 229376

    unsigned short* W3sw = (unsigned short*)d_ws;             // 128*1536*8 bf16 = 3 MB
    float* wsum  = (float*)(W3sw + (size_t)N_ * 1536 * 8);    // 16384
    float* bsum  = wsum + N_ * H_;                            // 128
    float* bia_g = bsum + N_;                                 // 49152

    k_pre<<<dim3(N_, 7), dim3(256), 0, stream>>>(W_ih, W_fc, b_ih, b_hh, b_fc,
                                                 W3sw, wsum, bsum, bia_g);
    k_main<<<dim3(N_, B_), dim3(256), 0, stream>>>(x, W3sw, bia_g, wsum, bsum,
                                                   W_fc, b_fc, G, xhat);
}

// Round 10
// 114.486 us; speedup vs baseline: 1.4253x; 1.4253x over previous
//
#include <hip/hip_runtime.h>
#include <math.h>

#define B_  8
#define N_  128
#define T_  256
#define L_  32
#define H_  128
#define TT_ 224   // T - L

typedef float f4    __attribute__((ext_vector_type(4)));
typedef float f32x4 __attribute__((ext_vector_type(4)));
typedef short bf16x8 __attribute__((ext_vector_type(8)));

__device__ __forceinline__ unsigned pk2bf(float a, float b) {   // RNE bf16 pack
    unsigned ua = __float_as_uint(a), ub = __float_as_uint(b);
    ua = (ua + 0x7FFFu + ((ua >> 16) & 1u)) >> 16;
    ub = (ub + 0x7FFFu + ((ub >> 16) & 1u)) >> 16;
    return ua | (ub << 16);
}

// ---------------------------------------------------------------------------
// Kernel 0, grid (N, 7) x 256 (unchanged since R8 — correct & fast):
//  y=0..5: W_ih -> bf16 W3sw pre-swizzled per-lane MFMA B-frag order.
//  y=6:    wsum / bsum / fused bias.
// ---------------------------------------------------------------------------
__global__ __launch_bounds__(256)
void k_pre(const float* __restrict__ W_ih, const float* __restrict__ W_fc,
           const float* __restrict__ b_ih, const float* __restrict__ b_hh,
           const float* __restrict__ b_fc,
           unsigned short* __restrict__ W3sw, float* __restrict__ wsum,
           float* __restrict__ bsum, float* __restrict__ bia_g) {
    const int n   = blockIdx.x;
    const int pid = blockIdx.y;   // 0..6
    const int tid = threadIdx.x;
    if (pid < 6) {
        const int idx  = pid * 256 + tid;          // 0..1535
        const int fg   = idx >> 6;                 // 0..23
        const int lane = idx & 63;
        const int col  = lane & 15, quad = lane >> 4;
        const int g    = fg % 3, ht = fg / 3;
        const int r    = g * 128 + ht * 16 + col;
        const int sr   = r + (r >= 128 ? 128 : 0);
        const f4* src = (const f4*)(W_ih + (size_t)n * 512 * L_ + sr * L_ + quad * 8);
        f4 v0 = src[0], v1 = src[1];
        uint4 out;
        out.x = pk2bf(v0.x, v0.y); out.y = pk2bf(v0.z, v0.w);
        out.z = pk2bf(v1.x, v1.y); out.w = pk2bf(v1.z, v1.w);
        *(uint4*)&W3sw[((size_t)n * 1536 + idx) * 8] = out;
    } else {
        __shared__ f4 part[8][32];
        __shared__ float bp[2];
        {   // wsum: thread (jg=tid>>5, h4=tid&31) sums 16 j
            const int h4 = tid & 31, jg = tid >> 5;
            const f4* Wf = (const f4*)(W_fc + (size_t)n * N_ * H_) + (size_t)jg * 16 * 32 + h4;
            f4 s = {0.f, 0.f, 0.f, 0.f};
            #pragma unroll
            for (int j = 0; j < 16; ++j) s += Wf[j * 32];
            part[jg][h4] = s;
        }
        if (tid < 128) {   // bsum partials
            float bv = b_fc[n * N_ + tid];
            #pragma unroll
            for (int off = 32; off > 0; off >>= 1) bv += __shfl_down(bv, off, 64);
            if ((tid & 63) == 0) bp[tid >> 6] = bv;
        }
        for (int i = tid; i < 384; i += 256) {
            const int sr = i + (i >= 128 ? 128 : 0);
            bia_g[n * 384 + i] = b_ih[(size_t)n * 512 + sr] + b_hh[(size_t)n * 512 + sr];
        }
        __syncthreads();
        if (tid < 32) {
            f4 s = part[0][tid];
            #pragma unroll
            for (int jg = 1; jg < 8; ++jg) s += part[jg][tid];
            *(f4*)&wsum[n * H_ + tid * 4] = s;
        }
        if (tid == 0) bsum[n] = bp[0] + bp[1];
    }
}

// ---------------------------------------------------------------------------
// Kernel 1: per (n,b) block, 4 waves. R10 = R8 skeleton (shuffle X_hat
// reduction — R9's LDS atomics serialized the kernel, reverted) with:
//  - A-frags PRE-BUILT once into xA[14][64] (uint4): the R8/R9-identical
//    725K SQ_LDS_BANK_CONFLICT came from the per-ttile xeo[p][base+q]
//    ds_read_b32 pattern (NOT the bpermutes — falsified by R9's unchanged
//    counter). Build pays that pattern once (1 pass, 1 wave-equivalent);
//    the K-loop then does ONE ds_read_b128 per ttile at lane*16 B —
//    lane-stride 4 banks, 2-way aliasing = free.
//  - 6-trans fused activation kept from R9 (2 rcp/element, exact algebra).
// ---------------------------------------------------------------------------
__global__ __launch_bounds__(256)
__attribute__((amdgpu_waves_per_eu(4, 4)))
void k_main(const float* __restrict__ x,
            const unsigned short* __restrict__ W3sw,
            const float* __restrict__ bia_g,
            const float* __restrict__ wsum, const float* __restrict__ bsum,
            const float* __restrict__ W_fc, const float* __restrict__ b_fc,
            float* __restrict__ G, float* __restrict__ xhat) {
    const int n   = blockIdx.x;
    const int b   = blockIdx.y;
    const int tid = threadIdx.x;
    const int w    = tid >> 6;    // wave 0..3
    const int lane = tid & 63;
    const int col  = lane & 15;   // MFMA m/n index
    const int quad = lane >> 4;   // MFMA k-group / row-group

    __shared__ float xs[258];
    __shared__ unsigned xeo[2][128];   // bf16 pairs: [0]=even-start, [1]=shift-1
    __shared__ float xr[TT_];
    __shared__ uint4 xA[14 * 64];      // per-lane A-frags, 14 KB
    __shared__ float xh_part[4][TT_];
    __shared__ float hd_loc[H_];
    __shared__ float red[4];

    // ---- B-frags: 6 coalesced 16B loads (pre-swizzled) ----
    const uint4* wsw = (const uint4*)W3sw + (size_t)n * 24 * 64 + lane;
    union { uint4 u; bf16x8 v; } bfr[2][3];
    float biaL[2][3], wshL[2];
    #pragma unroll
    for (int ht2 = 0; ht2 < 2; ++ht2) {
        const int ht = 2 * w + ht2;
        #pragma unroll
        for (int g = 0; g < 3; ++g) {
            bfr[ht2][g].u = wsw[(size_t)(ht * 3 + g) * 64];
            biaL[ht2][g]  = bia_g[n * 384 + g * 128 + ht * 16 + col];
        }
        wshL[ht2] = wsum[n * H_ + ht * 16 + col];
    }
    const float bsum_n = bsum[n];

    // ---- stage x ----
    xs[tid] = x[((size_t)b * N_ + n) * T_ + tid];
    if (tid < 2) xs[256 + tid] = 0.f;
    __syncthreads();
    if (tid < TT_) xr[tid] = 1.0f / xs[L_ + tid];
    if (tid < 128) {
        xeo[0][tid] = pk2bf(xs[2 * tid],     xs[2 * tid + 1]);
        xeo[1][tid] = pk2bf(xs[2 * tid + 1], xs[2 * tid + 2]);
    }
    __syncthreads();
    // ---- pre-build per-lane A-frags (the conflicted pattern, paid once) ----
    for (int e = tid; e < 14 * 64; e += 256) {
        const int tt = e >> 6, ln = e & 63;
        const int s  = tt * 16 + (ln & 15) + (ln >> 4) * 8;
        const int p  = s & 1, base = s >> 1;
        uint4 v;
        v.x = xeo[p][base + 0]; v.y = xeo[p][base + 1];
        v.z = xeo[p][base + 2]; v.w = xeo[p][base + 3];
        xA[e] = v;
    }
    __syncthreads();

    float hd_acc[2] = {0.f, 0.f};
    const f32x4 zero4 = {0.f, 0.f, 0.f, 0.f};

    #pragma unroll 2
    for (int ttile = 0; ttile < 14; ++ttile) {
        union { uint4 u; bf16x8 v; } af;
        af.u = xA[ttile * 64 + lane];          // one clean ds_read_b128

        const f4 xr4 = *(const f4*)&xr[ttile * 16 + quad * 4];
        float px[4] = {0.f, 0.f, 0.f, 0.f};

        #pragma unroll
        for (int ht2 = 0; ht2 < 2; ++ht2) {
            f32x4 ai = __builtin_amdgcn_mfma_f32_16x16x32_bf16(af.v, bfr[ht2][0].v, zero4, 0, 0, 0);
            f32x4 ag = __builtin_amdgcn_mfma_f32_16x16x32_bf16(af.v, bfr[ht2][1].v, zero4, 0, 0, 0);
            f32x4 ao = __builtin_amdgcn_mfma_f32_16x16x32_bf16(af.v, bfr[ht2][2].v, zero4, 0, 0, 0);
            #pragma unroll
            for (int reg = 0; reg < 4; ++reg) {
                const float gi = ai[reg] + biaL[ht2][0];
                const float gg = ag[reg] + biaL[ht2][1];
                const float go = ao[reg] + biaL[ht2][2];
                // c = sig(gi)*tanh(gg): single-rcp exact form
                const float e1 = __expf(-gi);
                const float e2 = __expf(gg + gg);
                const float c  = (e2 - 1.f) *
                    __builtin_amdgcn_rcpf((1.f + e1) * (e2 + 1.f));
                // hh = sig(go)*tanh(c)
                const float e3 = __expf(-go);
                const float e4 = __expf(c + c);
                const float hh = (e4 - 1.f) *
                    __builtin_amdgcn_rcpf((1.f + e3) * (e4 + 1.f));
                hd_acc[ht2] = fmaf(hh, xr4[reg], hd_acc[ht2]);
                px[reg]     = fmaf(hh, wshL[ht2], px[reg]);
            }
        }
        // X_hat partial: sum over this wave's 32 h (in-lane) then 16 n-lanes
        #pragma unroll
        for (int reg = 0; reg < 4; ++reg) {
            float pv = px[reg];
            pv += __shfl_xor(pv, 1, 64);
            pv += __shfl_xor(pv, 2, 64);
            pv += __shfl_xor(pv, 4, 64);
            pv += __shfl_xor(pv, 8, 64);
            if (col == 0) xh_part[w][ttile * 16 + quad * 4 + reg] = pv;
        }
    }

    // ---- Hd -> LDS (reduce across quads), Dinv partials ----
    #pragma unroll
    for (int ht2 = 0; ht2 < 2; ++ht2) {
        float v = hd_acc[ht2];
        v += __shfl_xor(v, 16, 64);
        v += __shfl_xor(v, 32, 64);
        if (lane < 16) hd_loc[(2 * w + ht2) * 16 + lane] = v;
    }
    {
        float dv = (tid < TT_) ? xr[tid] : 0.f;
        #pragma unroll
        for (int off = 32; off > 0; off >>= 1) dv += __shfl_down(dv, off, 64);
        if (lane == 0) red[w] = dv;
    }
    __syncthreads();

    // ---- X_hat writeout ----
    if (tid < TT_) {
        const float v = xh_part[0][tid] + xh_part[1][tid] +
                        xh_part[2][tid] + xh_part[3][tid];
        xhat[((size_t)b * TT_ + tid) * N_ + n] = v + bsum_n + 1e-6f;
    }

    // ---- fused G epilogue: thread pair (j, half) sums 64 h each ----
    {
        const float dinv = red[0] + red[1] + red[2] + red[3];
        const int j    = tid >> 1;
        const int half = tid & 1;
        const f4* Wf = (const f4*)(W_fc + ((size_t)n * N_ + j) * H_ + half * 64);
        float s = 0.f;
        #pragma unroll
        for (int q = 0; q < 16; ++q) {
            const f4 wv = Wf[q];
            const int hb = half * 64 + q * 4;
            s = fmaf(wv.x, hd_loc[hb + 0],
                fmaf(wv.y, hd_loc[hb + 1],
                fmaf(wv.z, hd_loc[hb + 2],
                fmaf(wv.w, hd_loc[hb + 3], s))));
        }
        s += __shfl_xor(s, 1, 64);
        if (half == 0) {
            const float bj = b_fc[n * N_ + j];
            G[(size_t)b * N_ * N_ + (size_t)j * N_ + n] =
                (s + bj * dinv) * (1.0f / 224.0f);
        }
    }
}

// ---------------------------------------------------------------------------
extern "C" void kernel_launch(void* const* d_in, const int* in_sizes, int n_in,
                              void* d_out, int out_size, void* d_ws, size_t ws_size,
                              hipStream_t stream) {
    const float* x    = (const float*)d_in[0];
    const float* W_ih = (const float*)d_in[1];
    const float* b_ih = (const float*)d_in[2];
    const float* b_hh = (const float*)d_in[3];
    const float* W_fc = (const float*)d_in[4];
    const float* b_fc = (const float*)d_in[5];

    float* G    = (float*)d_out;                        // B*N*N = 131072
    float* xhat = (float*)d_out + (size_t)B_ * N_ * N_; // B*TT*N = 229376

    unsigned short* W3sw = (unsigned short*)d_ws;             // 128*1536*8 bf16 = 3 MB
    float* wsum  = (float*)(W3sw + (size_t)N_ * 1536 * 8);    // 16384
    float* bsum  = wsum + N_ * H_;                            // 128
    float* bia_g = bsum + N_;                                 // 49152

    k_pre<<<dim3(N_, 7), dim3(256), 0, stream>>>(W_ih, W_fc, b_ih, b_hh, b_fc,
                                                 W3sw, wsum, bsum, bia_g);
    k_main<<<dim3(N_, B_), dim3(256), 0, stream>>>(x, W3sw, bia_g, wsum, bsum,
                                                   W_fc, b_fc, G, xhat);
}